// Round 6
// baseline (213.318 us; speedup 1.0000x reference)
//
#include <hip/hip_runtime.h>
#include <hip/hip_bf16.h>
#include <math.h>

// Problem constants (from reference setup_inputs)
constexpr int B   = 2;
constexpr int P   = 19248;
constexpr int N   = 100;   // TOP_K_CONF
constexpr int K   = 20;    // TOP_K_IOU
constexpr int HP  = 138;   // proto H/W
constexpr int HPP = HP * HP;
constexpr int H   = 550;
constexpr int W   = 550;
constexpr int DM  = 32;    // mask dim
constexpr float EPS = 1e-6f;
constexpr int NBIN = 2048;              // histogram bins over f32 bits >> 19
constexpr int CAND = 2048;              // candidate cap (expected ~150/batch)
constexpr int NPAIR = N * (N - 1) / 2;  // 4950
constexpr int DGRID = 64;               // k_det blocks (trivially co-resident)
constexpr int TS = 32;                  // output tile side (k_var)
constexpr int TG = (W + TS - 1) / TS;   // 18 -> 324 tiles

// Workspace layout (4-byte word offsets; int/float regions disjoint)
constexpr int OFS_IDX   = 0;                      // int   [B,N]
constexpr int OFS_SCONF = OFS_IDX   + B * N;      // float [B,N]
constexpr int OFS_SLOC  = OFS_SCONF + B * N;      // float [B,N,4]
constexpr int OFS_IOU   = OFS_SLOC  + B * N * 4;  // float [B,N,N] (upper tri)
constexpr int OFS_KLOC  = OFS_IOU   + B * N * N;  // float [B,K,4]
constexpr int OFS_KMASK = OFS_KLOC  + B * K * 4;  // float [B,K,32]
constexpr int OFS_KCONF = OFS_KMASK + B * K * DM; // float [B,K]
constexpr int OFS_BAR   = OFS_KCONF + B * K;      // uint  [2] (memset 0)

// Grid barrier for DGRID co-resident blocks. Arrival: ONE atomic RMW per
// block (release). Spin: atomic LOADS only (no RMW serialization at L2)
// + s_sleep to throttle poll traffic.
__device__ __forceinline__ void grid_barrier(unsigned int* cnt) {
  __syncthreads();
  if (threadIdx.x == 0) {
    __threadfence();  // make this block's prior global writes visible (agent)
    __hip_atomic_fetch_add(cnt, 1u, __ATOMIC_RELEASE, __HIP_MEMORY_SCOPE_AGENT);
    while (__hip_atomic_load(cnt, __ATOMIC_ACQUIRE, __HIP_MEMORY_SCOPE_AGENT) <
           (unsigned)DGRID) {
      __builtin_amdgcn_s_sleep(8);  // ~512 cycles between polls
    }
    __threadfence();
  }
  __syncthreads();
}

// ---------------------------------------------------------------------------
// Kernel 1 (k_det): topk (blocks 0..B-1) -> bar -> pairwise gaussian IoU
// (all blocks, one pair per wave) -> bar -> select/ae (blocks 0..B-1).
// ---------------------------------------------------------------------------
__global__ __launch_bounds__(1024) void k_det(
    const float* __restrict__ loc, const float* __restrict__ conf,
    const float* __restrict__ mask, float* __restrict__ wsf,
    int* __restrict__ wsi, unsigned int* __restrict__ bar,
    float* __restrict__ out) {
  const int blk = blockIdx.x;
  const int t = threadIdx.x;

  __shared__ float smem[N * N];   // 40 KB, reused: A = hist|cv|ci, C = siou
  __shared__ float outv[N];
  __shared__ int   outi[N];
  __shared__ float sconf[N];
  __shared__ unsigned int mbits[N];
  __shared__ int   keep[K];
  __shared__ float coef[K];
  __shared__ float red[16];
  __shared__ int   s_T, s_cnt;

  // ================= Phase A: fused exact stable top-100 (blocks 0..B-1) ====
  if (blk < B) {
    const int b = blk;
    if (b == 0 && t < 2) out[t] = 0.0f;
    int*   hist = (int*)smem;               // [0, 2048)
    float* cv   = smem + NBIN;              // [2048, 4096)
    int*   ci   = (int*)(smem + 2 * NBIN);  // [4096, 6144)
    constexpr int EPT = (P + 1023) / 1024;  // 19

    for (int q = t; q < NBIN; q += 1024) hist[q] = 0;
    if (t == 0) s_cnt = 0;
    __syncthreads();

    float v[EPT];
#pragma unroll
    for (int j = 0; j < EPT; j++) {
      int p = j * 1024 + t;
      if (p < P) {
        float c0 = conf[(b * P + p) * 2 + 0];
        float c1 = conf[(b * P + p) * 2 + 1];
        float m  = fmaxf(c0, c1);
        float e0 = expf(c0 - m), e1 = expf(c1 - m);
        v[j] = e1 / (e0 + e1);  // softmax[...,1]
        atomicAdd(&hist[__float_as_uint(v[j]) >> 19], 1);
      } else {
        v[j] = -1.0f;
      }
    }
    __syncthreads();

    if (t == 0) {  // threshold: smallest bin with cum-from-top >= N
      int acc = 0, bin = NBIN - 1;
      for (; bin >= 0; bin--) { acc += hist[bin]; if (acc >= N) break; }
      s_T = bin;
    }
    __syncthreads();
    const int T = s_T;

#pragma unroll
    for (int j = 0; j < EPT; j++) {
      int p = j * 1024 + t;
      if (p < P && (int)(__float_as_uint(v[j]) >> 19) >= T) {
        int pos = atomicAdd(&s_cnt, 1);
        if (pos < CAND) { cv[pos] = v[j]; ci[pos] = p; }
      }
    }
    __syncthreads();
    const int M = min(s_cnt, CAND);

    // rank = #{j lex-before (val desc, idx asc)}; ranks unique; rank<N kept
#pragma unroll
    for (int q = 0; q < CAND / 1024; q++) {
      int c = t + q * 1024;
      if (c < M) {
        float mv = cv[c]; int mi = ci[c];
        int rank = 0;
        for (int j = 0; j < M; j++) {
          float jv = cv[j]; int ji = ci[j];
          rank += (jv > mv || (jv == mv && ji < mi)) ? 1 : 0;
        }
        if (rank < N) { outv[rank] = mv; outi[rank] = mi; }
      }
    }
    __syncthreads();

    if (t < N) {
      wsi[OFS_IDX + b * N + t]   = outi[t];
      wsf[OFS_SCONF + b * N + t] = outv[t];
    }
    if (t < N * 4) {
      int k = t >> 2, d = t & 3;
      wsf[OFS_SLOC + (b * N + k) * 4 + d] = loc[(b * P + outi[k]) * 4 + d];
    }
  }
  grid_barrier(bar + 0);

  // ================= Phase B: gaussian IoU, one pair per wave ===============
  {
    const int lane = t & 63;
    const int wv = blk * 16 + (t >> 6);
    for (int pr = wv; pr < B * NPAIR; pr += DGRID * 16) {
      const int b = pr / NPAIR;
      const int r = pr - b * NPAIR;
      int i = (int)((199.0f - sqrtf((float)(39601 - 8 * r))) * 0.5f);
      i = min(max(i, 0), N - 2);
      while (i < N - 2 && ((i + 1) * (2 * N - 2 - i)) / 2 <= r) i++;
      while (i > 0 && (i * (2 * N - 1 - i)) / 2 > r) i--;
      const int j = i + 1 + (r - (i * (2 * N - 1 - i)) / 2);

      const float* li = &wsf[OFS_SLOC + (b * N + i) * 4];
      const float* lj = &wsf[OFS_SLOC + (b * N + j) * 4];
      const float cxi = li[0], cyi = li[1], wi = li[2], hi = li[3];
      const float cxj = lj[0], cyj = lj[1], wj = lj[2], hj = lj[3];

      float smin = 0.0f, ssi = 0.0f, ssj = 0.0f;
#pragma unroll
      for (int q = 0; q < 16; q++) {
        int pix = lane + q * 64;
        int y = pix >> 5, x = pix & 31;
        float xs = (x + 0.5f) / 32.0f, ys = (y + 0.5f) / 32.0f;
        float dxi = (xs - cxi) / (wi + 1e-4f);
        float dyi = (ys - cyi) / (hi + 1e-4f);
        float gi = expf(-0.5f * (dxi * dxi + dyi * dyi));
        float dxj = (xs - cxj) / (wj + 1e-4f);
        float dyj = (ys - cyj) / (hj + 1e-4f);
        float gj = expf(-0.5f * (dxj * dxj + dyj * dyj));
        smin += fminf(gi, gj);
        ssi += gi;
        ssj += gj;
      }
      for (int off = 32; off > 0; off >>= 1) {
        smin += __shfl_down(smin, off);
        ssi  += __shfl_down(ssi, off);
        ssj  += __shfl_down(ssj, off);
      }
      if (lane == 0)
        wsf[OFS_IOU + (b * N + i) * N + j] = smin / (ssi + ssj - smin);
    }
  }
  grid_barrier(bar + 1);

  // ================= Phase C: select + ae (blocks 0..B-1) ===================
  if (blk < B) {
    const int b = blk;
    float* siou = smem;  // [N*N]
    for (int idx = t; idx < N * N; idx += 1024) {
      int row = idx / N, col = idx - row * N;
      siou[idx] = (col > row) ? wsf[OFS_IOU + b * N * N + idx] : 0.0f;
    }
    if (t < N) { sconf[t] = wsf[OFS_SCONF + b * N + t]; mbits[t] = 0u; }
    __syncthreads();

    for (int idx = t; idx < N * N; idx += 1024) {
      int col = idx % N;
      atomicMax(&mbits[col], __float_as_uint(siou[idx]));
    }
    __syncthreads();

    if (t < N) {  // stable bottom-K: rank by (val asc, idx asc)
      unsigned int vb = mbits[t];
      int rank = 0;
      for (int j = 0; j < N; j++) {
        unsigned int jb = mbits[j];
        rank += (jb < vb || (jb == vb && j < t)) ? 1 : 0;
      }
      if (rank < K) keep[rank] = t;
    }
    __syncthreads();

    if (t < K) {
      int r = keep[t];
      float c = sconf[r];
      wsf[OFS_KCONF + b * K + t] = c;
      const float* kl = &wsf[OFS_SLOC + (b * N + r) * 4];
      float ael = 0.25f * (kl[0]*kl[0] + kl[1]*kl[1] + kl[2]*kl[2] + kl[3]*kl[3]);
      coef[t] = ael * c;
    }
    if (t < K * 4) {
      int k = t >> 2, d = t & 3;
      wsf[OFS_KLOC + (b * K + k) * 4 + d] = wsf[OFS_SLOC + (b * N + keep[k]) * 4 + d];
    }
    if (t < K * DM) {
      int k = t >> 5, d = t & 31;
      int orig_i = wsi[OFS_IDX + b * N + keep[k]];
      wsf[OFS_KMASK + (b * K + k) * DM + d] = mask[(b * P + orig_i) * DM + d];
    }
    __syncthreads();

    float acc = 0.0f;
    for (int kc = t; kc < K * N; kc += 1024) {
      int k = kc / N, c = kc - k * N;
      int r = keep[k];
      if (c > r) acc += siou[r * N + c] * sconf[c] * coef[k];
    }
    for (int off = 32; off > 0; off >>= 1) acc += __shfl_down(acc, off);
    if ((t & 63) == 0) red[t >> 6] = acc;
    __syncthreads();
    if (t == 0) {
      float s = 0.0f;
      for (int w2 = 0; w2 < 16; w2++) s += red[w2];
      atomicAdd(out + 1, s * (1.0f / (float)(B * N * N)));
    }
  }
}

// ---------------------------------------------------------------------------
// Kernel 2 (k_var): one 32x32 output tile per block. Compute the 10x10x2 fc
// cell patch in LDS (fc never hits global), then bilinear + weighted variance.
// ---------------------------------------------------------------------------
__global__ __launch_bounds__(1024) void k_var(
    const float* __restrict__ original, const float* __restrict__ proto,
    const float* __restrict__ wsf, float* __restrict__ out) {
  const int t = threadIdx.x;
  __shared__ float kl[B * K * 4];
  __shared__ float kc[B * K];
  __shared__ float km[B * K * DM];
  __shared__ float dfc[B * 100];  // [B][10][10]
  __shared__ float red[16];

  if (t < B * K * 4) kl[t] = wsf[OFS_KLOC + t];
  if (t < B * K) kc[t] = wsf[OFS_KCONF + t];
  if (t < B * K * DM) km[t] = wsf[OFS_KMASK + t];

  const int tile = blockIdx.x;
  const int ty = tile / TG, tx = tile - ty * TG;
  const int h0 = ty * TS, w0 = tx * TS;
  const float sc = 138.0f / 550.0f;
  const int cy_base = (int)floorf((h0 + 0.5f) * sc - 0.5f);
  const int cx_base = (int)floorf((w0 + 0.5f) * sc - 0.5f);
  __syncthreads();

  if (t < B * 100) {  // one fc cell per thread
    int bb = t / 100, rem = t - bb * 100;
    int sy = rem / 10, sx = rem - sy * 10;
    int gy = min(HP - 1, max(0, cy_base + sy));
    int gx = min(HP - 1, max(0, cx_base + sx));
    float pv2[DM];
    const float4* pp = (const float4*)&proto[(size_t)(bb * HPP + gy * HP + gx) * DM];
#pragma unroll
    for (int q = 0; q < DM / 4; q++) {
      float4 f = pp[q];
      pv2[q*4+0] = f.x; pv2[q*4+1] = f.y; pv2[q*4+2] = f.z; pv2[q*4+3] = f.w;
    }
    const float ysv = (gy + 0.5f) / 138.0f;
    const float xsv = (gx + 0.5f) / 138.0f;
    float sum1 = 0.0f, sum2 = 0.0f;
#pragma unroll
    for (int k = 0; k < K; k++) {
      float dot = 0.0f;
#pragma unroll
      for (int d = 0; d < DM; d++) dot += pv2[d] * km[(bb * K + k) * DM + d];
      float a  = 1.0f / (1.0f + expf(-dot));
      float dx = (xsv - kl[(bb * K + k) * 4 + 0]) / (kl[(bb * K + k) * 4 + 2] + 1e-4f);
      float dy = (ysv - kl[(bb * K + k) * 4 + 1]) / (kl[(bb * K + k) * 4 + 3] + 1e-4f);
      float ug = expf(-0.5f * (dx * dx + dy * dy));
      float att = a * ug * kc[bb * K + k];
      sum1 += att;
      sum2 += att * att;
    }
    float fc = 1.0f - sum2 / (sum1 + EPS);
    if (fc != fc) fc = 0.0f;
    dfc[t] = fc;
  }
  __syncthreads();

  float vacc = 0.0f;
  const int h = h0 + (t >> 5), w2 = w0 + (t & 31);
  if (h < H && w2 < W) {
    float sy = (h + 0.5f) * sc - 0.5f;
    float sx = (w2 + 0.5f) * sc - 0.5f;
    float fy0 = floorf(sy), fx0 = floorf(sx);
    float wy = sy - fy0, wx = sx - fx0;
    int iy0 = (int)fy0 - cy_base;  // in [0,8]; slots hold edge-clamped cells
    int ix0 = (int)fx0 - cx_base;
    float r0, r1;
    {
      const float* fc = dfc;
      float v00 = fc[iy0*10+ix0], v01 = fc[iy0*10+ix0+1];
      float v10 = fc[(iy0+1)*10+ix0], v11 = fc[(iy0+1)*10+ix0+1];
      float top = v00 + (v01 - v00) * wx;
      float bot = v10 + (v11 - v10) * wx;
      r0 = top + (bot - top) * wy;
    }
    {
      const float* fc = dfc + 100;
      float v00 = fc[iy0*10+ix0], v01 = fc[iy0*10+ix0+1];
      float v10 = fc[(iy0+1)*10+ix0], v11 = fc[(iy0+1)*10+ix0+1];
      float top = v00 + (v01 - v00) * wx;
      float bot = v10 + (v11 - v10) * wx;
      r1 = top + (bot - top) * wy;
    }
    float total = r0 + r1;
    float inv_t = 1.0f / total;           // wmean: no eps
    float inv_te = 1.0f / (total + EPS);  // wvar: +eps
#pragma unroll
    for (int c = 0; c < 3; c++) {
      float o0 = original[((0 * 3 + c) * H + h) * W + w2];
      float o1 = original[((1 * 3 + c) * H + h) * W + w2];
      float wm = (o0 * r0 + o1 * r1) * inv_t;
      float d0 = o0 - wm, d1 = o1 - wm;
      vacc += (d0 * d0 * r0 + d1 * d1 * r1) * inv_te;
    }
  }
  for (int off = 32; off > 0; off >>= 1) vacc += __shfl_down(vacc, off);
  if ((t & 63) == 0) red[t >> 6] = vacc;
  __syncthreads();
  if (t == 0) {
    float s = 0.0f;
    for (int w3 = 0; w3 < 16; w3++) s += red[w3];
    atomicAdd(out + 0, s * ((float)B / (float)HP));
  }
}

// ---------------------------------------------------------------------------
extern "C" void kernel_launch(void* const* d_in, const int* in_sizes, int n_in,
                              void* d_out, int out_size, void* d_ws,
                              size_t ws_size, hipStream_t stream) {
  (void)in_sizes; (void)n_in; (void)out_size; (void)ws_size;
  const float* original = (const float*)d_in[0];
  const float* loc      = (const float*)d_in[1];
  const float* conf     = (const float*)d_in[2];
  const float* mask     = (const float*)d_in[3];
  const float* proto    = (const float*)d_in[4];
  float* out = (float*)d_out;
  float* wsf = (float*)d_ws;
  int*   wsi = (int*)d_ws;
  unsigned int* bar = (unsigned int*)(wsi + OFS_BAR);

  hipMemsetAsync(bar, 0, 2 * sizeof(unsigned int), stream);
  k_det<<<DGRID, 1024, 0, stream>>>(loc, conf, mask, wsf, wsi, bar, out);
  k_var<<<TG * TG, 1024, 0, stream>>>(original, proto, wsf, out);
}

// Round 9
// 138.278 us; speedup vs baseline: 1.5427x; 1.5427x over previous
//
#include <hip/hip_runtime.h>
#include <hip/hip_bf16.h>
#include <math.h>

// Problem constants (from reference setup_inputs)
constexpr int B   = 2;
constexpr int P   = 19248;
constexpr int N   = 100;   // TOP_K_CONF
constexpr int K   = 20;    // TOP_K_IOU
constexpr int HP  = 138;   // proto H/W
constexpr int HPP = HP * HP;
constexpr int H   = 550;
constexpr int W   = 550;
constexpr int DM  = 32;    // mask dim
constexpr float EPS = 1e-6f;
constexpr int NBIN = 2048;              // histogram bins over f32 bits >> 19
constexpr int CAND = 2048;              // candidate cap (expected ~150/batch)
constexpr int NPAIR = N * (N - 1) / 2;  // 4950
constexpr int WPB = 16;                 // waves per 1024-thread block
constexpr int TS = 32;                  // output tile side (k_var)
constexpr int TG = (W + TS - 1) / TS;   // 18 -> 324 tiles

// Workspace layout (4-byte word offsets; int/float regions disjoint)
constexpr int OFS_IDX   = 0;                      // int   [B,N]
constexpr int OFS_SCONF = OFS_IDX   + B * N;      // float [B,N]
constexpr int OFS_SLOC  = OFS_SCONF + B * N;      // float [B,N,4]
constexpr int OFS_IOU   = OFS_SLOC  + B * N * 4;  // float [B,N,N] (upper tri)
constexpr int OFS_KLOC  = OFS_IOU   + B * N * N;  // float [B,K,4]
constexpr int OFS_KMASK = OFS_KLOC  + B * K * 4;  // float [B,K,32]
constexpr int OFS_KCONF = OFS_KMASK + B * K * DM; // float [B,K]

// ---------------------------------------------------------------------------
// Kernel 1: fused exact stable top-100 per batch (one block per batch):
// sigmoid -> LDS hist -> threshold -> LDS compact -> O(M^2) rank -> gather.
// ---------------------------------------------------------------------------
__global__ __launch_bounds__(1024) void k_topk(
    const float* __restrict__ conf, const float* __restrict__ loc,
    float* __restrict__ wsf, int* __restrict__ wsi, float* __restrict__ out) {
  const int b = blockIdx.x;
  const int t = threadIdx.x;
  constexpr int EPT = (P + 1023) / 1024;  // 19
  if (b == 0 && t < 2) out[t] = 0.0f;

  __shared__ int   hist[NBIN];
  __shared__ int   s_T, s_cnt;
  __shared__ float cv[CAND];
  __shared__ int   ci[CAND];
  __shared__ float outv[N];
  __shared__ int   outi[N];

  for (int q = t; q < NBIN; q += 1024) hist[q] = 0;
  if (t == 0) s_cnt = 0;
  __syncthreads();

  float v[EPT];
#pragma unroll
  for (int j = 0; j < EPT; j++) {
    int p = j * 1024 + t;
    if (p < P) {
      float c0 = conf[(b * P + p) * 2 + 0];
      float c1 = conf[(b * P + p) * 2 + 1];
      float m  = fmaxf(c0, c1);
      float e0 = expf(c0 - m), e1 = expf(c1 - m);
      v[j] = e1 / (e0 + e1);  // softmax(...)[1]
      atomicAdd(&hist[__float_as_uint(v[j]) >> 19], 1);
    } else {
      v[j] = -1.0f;
    }
  }
  __syncthreads();

  if (t == 0) {  // smallest bin with cumulative-from-top >= N
    int acc = 0, bin = NBIN - 1;
    for (; bin >= 0; bin--) { acc += hist[bin]; if (acc >= N) break; }
    s_T = bin;
  }
  __syncthreads();
  const int T = s_T;

#pragma unroll
  for (int j = 0; j < EPT; j++) {
    int p = j * 1024 + t;
    if (p < P && (int)(__float_as_uint(v[j]) >> 19) >= T) {
      int pos = atomicAdd(&s_cnt, 1);
      if (pos < CAND) { cv[pos] = v[j]; ci[pos] = p; }
    }
  }
  __syncthreads();
  const int M = min(s_cnt, CAND);

  // rank = #{j lex-before (val desc, idx asc)} == lax.top_k stable order
#pragma unroll
  for (int q = 0; q < CAND / 1024; q++) {
    int c = t + q * 1024;
    if (c < M) {
      float mv = cv[c]; int mi = ci[c];
      int rank = 0;
      for (int j = 0; j < M; j++) {
        float jv = cv[j]; int ji = ci[j];
        rank += (jv > mv || (jv == mv && ji < mi)) ? 1 : 0;
      }
      if (rank < N) { outv[rank] = mv; outi[rank] = mi; }
    }
  }
  __syncthreads();

  if (t < N) {
    wsi[OFS_IDX + b * N + t]   = outi[t];
    wsf[OFS_SCONF + b * N + t] = outv[t];
  }
  if (t < N * 4) {
    int k = t >> 2, d = t & 3;
    wsf[OFS_SLOC + (b * N + k) * 4 + d] = loc[(b * P + outi[k]) * 4 + d];
  }
}

// ---------------------------------------------------------------------------
// Kernel 2: gaussian IoU, one upper-triangle pair per wave (16 pairs/block).
// Gaussians recomputed on the fly; inter, s_i, s_j reduced in-wave (no LDS).
// ---------------------------------------------------------------------------
__global__ __launch_bounds__(1024) void k_iou(float* __restrict__ wsf) {
  const int t = threadIdx.x;
  const int lane = t & 63;
  const int pr = blockIdx.x * WPB + (t >> 6);
  if (pr >= B * NPAIR) return;
  const int b = pr / NPAIR;
  const int r = pr - b * NPAIR;
  // decode r -> (i, j), i<j: base(i) = i*(2N-1-i)/2
  int i = (int)((199.0f - sqrtf((float)(39601 - 8 * r))) * 0.5f);
  i = min(max(i, 0), N - 2);
  while (i < N - 2 && ((i + 1) * (2 * N - 2 - i)) / 2 <= r) i++;
  while (i > 0 && (i * (2 * N - 1 - i)) / 2 > r) i--;
  const int j = i + 1 + (r - (i * (2 * N - 1 - i)) / 2);

  const float* li = &wsf[OFS_SLOC + (b * N + i) * 4];
  const float* lj = &wsf[OFS_SLOC + (b * N + j) * 4];
  const float cxi = li[0], cyi = li[1], wi = li[2], hi = li[3];
  const float cxj = lj[0], cyj = lj[1], wj = lj[2], hj = lj[3];

  float smin = 0.0f, ssi = 0.0f, ssj = 0.0f;
#pragma unroll
  for (int q = 0; q < 16; q++) {
    int pix = lane + q * 64;
    int y = pix >> 5, x = pix & 31;
    float xs = (x + 0.5f) / 32.0f, ys = (y + 0.5f) / 32.0f;
    float dxi = (xs - cxi) / (wi + 1e-4f);
    float dyi = (ys - cyi) / (hi + 1e-4f);
    float gi = expf(-0.5f * (dxi * dxi + dyi * dyi));
    float dxj = (xs - cxj) / (wj + 1e-4f);
    float dyj = (ys - cyj) / (hj + 1e-4f);
    float gj = expf(-0.5f * (dxj * dxj + dyj * dyj));
    smin += fminf(gi, gj);
    ssi += gi;
    ssj += gj;
  }
  for (int off = 32; off > 0; off >>= 1) {
    smin += __shfl_down(smin, off);
    ssi  += __shfl_down(ssi, off);
    ssj  += __shfl_down(ssj, off);
  }
  if (lane == 0)
    wsf[OFS_IOU + (b * N + i) * N + j] = smin / (ssi + ssj - smin);
}

// ---------------------------------------------------------------------------
// Kernel 3: fully-parallel select: upper-tri iou staged to LDS (lower = 0),
// column max via LDS atomicMax on bits, rank-based stable bottom-20,
// gathers, ae loss.
// ---------------------------------------------------------------------------
__global__ __launch_bounds__(1024) void k_select(
    const float* __restrict__ mask, float* __restrict__ wsf,
    int* __restrict__ wsi, float* __restrict__ out) {
  const int b = blockIdx.x;
  const int t = threadIdx.x;
  __shared__ float siou[N * N];        // 40 KB
  __shared__ float sconf[N];
  __shared__ unsigned int mbits[N];
  __shared__ int   keep[K];
  __shared__ float coef[K];
  __shared__ float red[16];

  for (int idx = t; idx < N * N; idx += 1024) {
    int row = idx / N, col = idx - row * N;
    siou[idx] = (col > row) ? wsf[OFS_IOU + b * N * N + idx] : 0.0f;
  }
  if (t < N) { sconf[t] = wsf[OFS_SCONF + b * N + t]; mbits[t] = 0u; }
  __syncthreads();

  // column max (triu semantics: lower already 0; iou > 0)
  for (int idx = t; idx < N * N; idx += 1024) {
    int col = idx % N;
    atomicMax(&mbits[col], __float_as_uint(siou[idx]));
  }
  __syncthreads();

  if (t < N) {  // stable bottom-K: rank by (val asc, idx asc)
    unsigned int vb = mbits[t];
    int rank = 0;
    for (int j = 0; j < N; j++) {
      unsigned int jb = mbits[j];
      rank += (jb < vb || (jb == vb && j < t)) ? 1 : 0;
    }
    if (rank < K) keep[rank] = t;
  }
  __syncthreads();

  if (t < K) {
    int r = keep[t];
    float c = sconf[r];
    wsf[OFS_KCONF + b * K + t] = c;
    const float* kl = &wsf[OFS_SLOC + (b * N + r) * 4];
    float ael = 0.25f * (kl[0]*kl[0] + kl[1]*kl[1] + kl[2]*kl[2] + kl[3]*kl[3]);
    coef[t] = ael * c;
  }
  if (t < K * 4) {
    int k = t >> 2, d = t & 3;
    wsf[OFS_KLOC + (b * K + k) * 4 + d] = wsf[OFS_SLOC + (b * N + keep[k]) * 4 + d];
  }
  if (t < K * DM) {
    int k = t >> 5, d = t & 31;
    int orig_i = wsi[OFS_IDX + b * N + keep[k]];
    wsf[OFS_KMASK + (b * K + k) * DM + d] = mask[(b * P + orig_i) * DM + d];
  }
  __syncthreads();

  float acc = 0.0f;
  for (int kc = t; kc < K * N; kc += 1024) {
    int k = kc / N, c = kc - k * N;
    int r = keep[k];
    if (c > r) acc += siou[r * N + c] * sconf[c] * coef[k];
  }
  for (int off = 32; off > 0; off >>= 1) acc += __shfl_down(acc, off);
  if ((t & 63) == 0) red[t >> 6] = acc;
  __syncthreads();
  if (t == 0) {
    float s = 0.0f;
    for (int w2 = 0; w2 < 16; w2++) s += red[w2];
    atomicAdd(out + 1, s * (1.0f / (float)(B * N * N)));
  }
}

// ---------------------------------------------------------------------------
// Kernel 4: one 32x32 output tile per block. Compute the 10x10x2 fc cell
// patch in LDS (fc never hits global), then bilinear + weighted variance.
// NOTE: all LDS staging uses strided loops — B*K*DM = 1280 > blockDim (1024);
// the round-6/7 `if (t < 1280)` staging left 256 entries unwritten (the bug).
// ---------------------------------------------------------------------------
__global__ __launch_bounds__(1024) void k_var(
    const float* __restrict__ original, const float* __restrict__ proto,
    const float* __restrict__ wsf, float* __restrict__ out) {
  const int t = threadIdx.x;
  __shared__ float kl[B * K * 4];
  __shared__ float kc[B * K];
  __shared__ float km[B * K * DM];
  __shared__ float dfc[B * 100];  // [B][10][10]
  __shared__ float red[16];

  for (int q = t; q < B * K * 4; q += 1024) kl[q] = wsf[OFS_KLOC + q];
  for (int q = t; q < B * K; q += 1024) kc[q] = wsf[OFS_KCONF + q];
  for (int q = t; q < B * K * DM; q += 1024) km[q] = wsf[OFS_KMASK + q];

  const int tile = blockIdx.x;
  const int ty = tile / TG, tx = tile - ty * TG;
  const int h0 = ty * TS, w0 = tx * TS;
  const float sc = 138.0f / 550.0f;
  const int cy_base = (int)floorf((h0 + 0.5f) * sc - 0.5f);
  const int cx_base = (int)floorf((w0 + 0.5f) * sc - 0.5f);
  __syncthreads();

  if (t < B * 100) {  // one fc cell per thread (edge-clamped cell coords)
    int bb = t / 100, rem = t - bb * 100;
    int sy = rem / 10, sx = rem - sy * 10;
    int gy = min(HP - 1, max(0, cy_base + sy));
    int gx = min(HP - 1, max(0, cx_base + sx));
    float pv2[DM];
    const float4* pp = (const float4*)&proto[(size_t)(bb * HPP + gy * HP + gx) * DM];
#pragma unroll
    for (int q = 0; q < DM / 4; q++) {
      float4 f = pp[q];
      pv2[q*4+0] = f.x; pv2[q*4+1] = f.y; pv2[q*4+2] = f.z; pv2[q*4+3] = f.w;
    }
    const float ysv = (gy + 0.5f) / 138.0f;
    const float xsv = (gx + 0.5f) / 138.0f;
    float sum1 = 0.0f, sum2 = 0.0f;
#pragma unroll
    for (int k = 0; k < K; k++) {
      float dot = 0.0f;
#pragma unroll
      for (int d = 0; d < DM; d++) dot += pv2[d] * km[(bb * K + k) * DM + d];
      float a  = 1.0f / (1.0f + expf(-dot));
      float dx = (xsv - kl[(bb * K + k) * 4 + 0]) / (kl[(bb * K + k) * 4 + 2] + 1e-4f);
      float dy = (ysv - kl[(bb * K + k) * 4 + 1]) / (kl[(bb * K + k) * 4 + 3] + 1e-4f);
      float ug = expf(-0.5f * (dx * dx + dy * dy));
      float att = a * ug * kc[bb * K + k];
      sum1 += att;
      sum2 += att * att;
    }
    float fc = 1.0f - sum2 / (sum1 + EPS);
    if (fc != fc) fc = 0.0f;
    dfc[t] = fc;
  }
  __syncthreads();

  float vacc = 0.0f;
  const int h = h0 + (t >> 5), w2 = w0 + (t & 31);
  if (h < H && w2 < W) {
    float sy = (h + 0.5f) * sc - 0.5f;
    float sx = (w2 + 0.5f) * sc - 0.5f;
    float fy0 = floorf(sy), fx0 = floorf(sx);
    float wy = sy - fy0, wx = sx - fx0;
    int iy0 = (int)fy0 - cy_base;  // in [0,8]; slots hold edge-clamped cells
    int ix0 = (int)fx0 - cx_base;
    float r0, r1;
    {
      const float* fc = dfc;
      float v00 = fc[iy0*10+ix0], v01 = fc[iy0*10+ix0+1];
      float v10 = fc[(iy0+1)*10+ix0], v11 = fc[(iy0+1)*10+ix0+1];
      float top = v00 + (v01 - v00) * wx;
      float bot = v10 + (v11 - v10) * wx;
      r0 = top + (bot - top) * wy;
    }
    {
      const float* fc = dfc + 100;
      float v00 = fc[iy0*10+ix0], v01 = fc[iy0*10+ix0+1];
      float v10 = fc[(iy0+1)*10+ix0], v11 = fc[(iy0+1)*10+ix0+1];
      float top = v00 + (v01 - v00) * wx;
      float bot = v10 + (v11 - v10) * wx;
      r1 = top + (bot - top) * wy;
    }
    float total = r0 + r1;
    float inv_t = 1.0f / total;           // wmean: no eps
    float inv_te = 1.0f / (total + EPS);  // wvar: +eps
#pragma unroll
    for (int c = 0; c < 3; c++) {
      float o0 = original[((0 * 3 + c) * H + h) * W + w2];
      float o1 = original[((1 * 3 + c) * H + h) * W + w2];
      float wm = (o0 * r0 + o1 * r1) * inv_t;
      float d0 = o0 - wm, d1 = o1 - wm;
      vacc += (d0 * d0 * r0 + d1 * d1 * r1) * inv_te;
    }
  }
  for (int off = 32; off > 0; off >>= 1) vacc += __shfl_down(vacc, off);
  if ((t & 63) == 0) red[t >> 6] = vacc;
  __syncthreads();
  if (t == 0) {
    float s = 0.0f;
    for (int w3 = 0; w3 < 16; w3++) s += red[w3];
    atomicAdd(out + 0, s * ((float)B / (float)HP));
  }
}

// ---------------------------------------------------------------------------
extern "C" void kernel_launch(void* const* d_in, const int* in_sizes, int n_in,
                              void* d_out, int out_size, void* d_ws,
                              size_t ws_size, hipStream_t stream) {
  (void)in_sizes; (void)n_in; (void)out_size; (void)ws_size;
  const float* original = (const float*)d_in[0];
  const float* loc      = (const float*)d_in[1];
  const float* conf     = (const float*)d_in[2];
  const float* mask     = (const float*)d_in[3];
  const float* proto    = (const float*)d_in[4];
  float* out = (float*)d_out;
  float* wsf = (float*)d_ws;
  int*   wsi = (int*)d_ws;

  k_topk<<<B, 1024, 0, stream>>>(conf, loc, wsf, wsi, out);
  k_iou<<<(B * NPAIR + WPB - 1) / WPB, 1024, 0, stream>>>(wsf);
  k_select<<<B, 1024, 0, stream>>>(mask, wsf, wsi, out);
  k_var<<<TG * TG, 1024, 0, stream>>>(original, proto, wsf, out);
}